// Round 15
// baseline (183.083 us; speedup 1.0000x reference)
//
#include <hip/hip_runtime.h>
#include <cmath>

#define KK 16
#define HID 256
#define NROWH 30720   // P*BS = 120*256
#define NROW 61440
#define GM 4096       // BS*K
#define GK 512        // FT
#define GN 512        // 2*HID
#define EPSV 1e-5f
#define SLOPEV 0.01f

#define BM 64
#define BN 64
#define BK 16
#define NT 32         // K iterations (512/16)
#define NSTATB 960

// ---------------- K1: UV = X(4096x512) @ [W1_top | W1_bot](512x512) + b1
// grid 512 (2 blocks/CU, 8 waves/CU), 4x4 per thread, double-buffered LDS
__global__ __launch_bounds__(256) void k_gemm(const float* __restrict__ X,
                                              const float* __restrict__ W1,
                                              const float* __restrict__ b1,
                                              float* __restrict__ UV,
                                              float* __restrict__ zbuf) {
  // block 0 zeros sums8(4096) + lossAcc64(1024) + ticket(1) — consumed later
  if (blockIdx.x == 0) {
    for (int i = threadIdx.x; i < 5376; i += 256) zbuf[i] = 0.0f;
  }
  __shared__ float As[2][BK][68];   // k-major, padded 64->68 (2-way writes, free)
  __shared__ float Bs[2][BK][BN];
  // XCD swizzle: 8 consecutive M-panels per XCD (A panel 1MB + W1 1MB L2-resident)
  const int id  = blockIdx.x;            // 0..511
  const int xcd = id & 7, w8 = id >> 3;  // w8 0..63
  const int mt  = xcd * 8 + (w8 >> 3);   // 0..63
  const int nt  = w8 & 7;                // 0..7
  const int m0  = mt * BM, n0 = nt * BN;
  const float* Wb = (n0 < HID) ? (W1 + n0) : (W1 + GK * HID + (n0 - HID));
  const int t = threadIdx.x;
  // staging: A row am=t>>2 (0..63), k-quad aq=t&3 ; B row brr=t>>4, n-quad bq=t&15
  const int am = t >> 2, aq = t & 3;
  const int brr = t >> 4, bq = t & 15;
  // compute: m frag ty*4, n frag tx*4
  const int ty = t >> 4, tx = t & 15;

  const float* Xp = X + (size_t)(m0 + am) * GK;

  float4 a4, b4;
  float acc[4][4] = {};

  auto stage = [&](int it) {
    a4 = *(const float4*)(Xp + it * BK + aq * 4);
    b4 = *(const float4*)(Wb + (size_t)(it * BK + brr) * HID + bq * 4);
  };
  auto wr = [&](int buf) {
    As[buf][aq * 4 + 0][am] = a4.x;
    As[buf][aq * 4 + 1][am] = a4.y;
    As[buf][aq * 4 + 2][am] = a4.z;
    As[buf][aq * 4 + 3][am] = a4.w;
    *(float4*)&Bs[buf][brr][bq * 4] = b4;
  };

  stage(0);
  wr(0);
  __syncthreads();
  for (int it = 0; it < NT; ++it) {
    if (it + 1 < NT) stage(it + 1);            // next-tile global loads in flight
    const int buf = it & 1;
    #pragma unroll
    for (int kk = 0; kk < BK; ++kk) {
      float4 x = *(const float4*)&As[buf][kk][ty * 4];
      float4 y = *(const float4*)&Bs[buf][kk][tx * 4];
      float av[4] = {x.x, x.y, x.z, x.w};
      float bv[4] = {y.x, y.y, y.z, y.w};
      #pragma unroll
      for (int i = 0; i < 4; i++)
        #pragma unroll
        for (int j = 0; j < 4; j++)
          acc[i][j] = fmaf(av[i], bv[j], acc[i][j]);
    }
    if (it + 1 < NT) wr((it + 1) & 1);         // vmcnt wait lands here
    __syncthreads();
  }
  const int n = n0 + tx * 4;
  float4 add = {0.f, 0.f, 0.f, 0.f};
  if (n < HID) add = *(const float4*)&b1[n];   // block-uniform branch
  #pragma unroll
  for (int i = 0; i < 4; i++) {
    const int m = m0 + ty * 4 + i;
    float4 v = {acc[i][0] + add.x, acc[i][1] + add.y, acc[i][2] + add.z, acc[i][3] + add.w};
    *(float4*)&UV[(size_t)m * GN + n] = v;
  }
}

__device__ __forceinline__ void decode_pair(int p, int& iu, int& ju) {
  int i = 0, q = p;
  while (q >= 15 - i) { q -= 15 - i; i++; }
  iu = i; ju = i + 1 + q;
}

// ---------------- K2: per-feature sums of h, h^2; last block computes af/cf
__global__ __launch_bounds__(256) void k_stats(const float* __restrict__ UV,
                                               float* __restrict__ sums8,
                                               float* __restrict__ ticket,
                                               const float* __restrict__ gamma,
                                               const float* __restrict__ beta,
                                               float* __restrict__ af,
                                               float* __restrict__ cf) {
  const int bid = blockIdx.x;                    // 0..959
  const int blk = (bid & 7) * 120 + (bid >> 3);  // same-p blocks share an XCD
  const int p = blk >> 3;
  const int b0 = (blk & 7) * 32;
  const int f = threadIdx.x;                     // feature 0..255
  int iu, ju; decode_pair(p, iu, ju);
  float s1 = 0.f, s2 = 0.f;
  for (int b = b0; b < b0 + 32; b++) {
    const int bi  = (b * KK + iu) * GN;
    const int bj1 = (b * KK + ju) * GN + HID;
    const int bj2 = (((b - p - 1) & 255) * KK + ju) * GN + HID;
    float u  = UV[bi + f];
    float h1 = u + UV[bj1 + f];
    float h2 = u + UV[bj2 + f];
    s1 += h1 + h2;
    s2 += h1 * h1 + h2 * h2;
  }
  float* dst = sums8 + (bid & 7) * 512;
  atomicAdd(dst + f, s1);
  atomicAdd(dst + 256 + f, s2);
  // last-block-done: fold the finalize pass in
  __shared__ int lastFlag;
  __threadfence();
  __syncthreads();
  if (f == 0) {
    float old = atomicAdd(ticket, 1.0f);
    lastFlag = (old == (float)(NSTATB - 1)) ? 1 : 0;
  }
  __syncthreads();
  if (lastFlag) {
    float t1 = 0.f, t2 = 0.f;
    #pragma unroll
    for (int c = 0; c < 8; c++) {
      t1 += sums8[c * 512 + f];
      t2 += sums8[c * 512 + 256 + f];
    }
    float mean = t1 * (1.0f / NROW);
    float var  = t2 * (1.0f / NROW) - mean * mean;
    float a = gamma[f] * rsqrtf(var + EPSV);
    af[f] = a;
    cf[f] = beta[f] - mean * a;
  }
}

// ---------------- K3: scores + correct bits + BCE partials (fused)
__global__ __launch_bounds__(256) void k_scores(const float* __restrict__ UV,
                                                const float* __restrict__ af,
                                                const float* __restrict__ cf,
                                                const float* __restrict__ W2,
                                                const float* __restrict__ b2,
                                                float* __restrict__ out,
                                                float* __restrict__ lossAcc64) {
  const int bid = blockIdx.x;                    // 0..7679
  const int swz = (bid & 7) * 960 + (bid >> 3);  // same-p blocks share an XCD
  const int wv0 = swz * 4;
  const int w = threadIdx.x >> 6;
  const int lane = threadIdx.x & 63;
  const int wv = wv0 + w;
  const int p = wv >> 8, b = wv & 255;
  int iu, ju; decode_pair(p, iu, ju);
  const int bi  = (b * KK + iu) * GN;
  const int bj1 = (b * KK + ju) * GN + HID;
  const int bj2 = (((b - p - 1) & 255) * KK + ju) * GN + HID;
  float sp = 0.f, sn = 0.f;
  #pragma unroll
  for (int r = 0; r < 4; r++) {
    int f = lane + r * 64;
    float u = UV[bi + f];
    float a = af[f], c = cf[f], ww = W2[f];
    float h1 = fmaf(a, u + UV[bj1 + f], c);
    h1 = h1 >= 0.f ? h1 : SLOPEV * h1;
    sp = fmaf(ww, h1, sp);
    float h2 = fmaf(a, u + UV[bj2 + f], c);
    h2 = h2 >= 0.f ? h2 : SLOPEV * h2;
    sn = fmaf(ww, h2, sn);
  }
  #pragma unroll
  for (int off = 32; off > 0; off >>= 1) {
    sp += __shfl_xor(sp, off, 64);
    sn += __shfl_xor(sn, off, 64);
  }
  __shared__ float sc[8];
  __shared__ float sbce[8];
  if (lane == 0) {
    float bb = b2[0];
    sc[w]     = sp + bb;
    sc[4 + w] = sn + bb;
  }
  __syncthreads();
  const int t = threadIdx.x;
  if (t < 8) {
    const int j = t & 3;
    const bool pos = t < 4;
    const int row = (pos ? 0 : NROWH) + wv0 + j;
    const float s = sc[t];
    out[1 + row] = s;
    float bce = fmaxf(s, 0.f) - (pos ? s : 0.f) + log1pf(expf(-fabsf(s)));
    sbce[t] = bce;
    #pragma unroll
    for (int tt = 1; tt <= 9; tt++) {
      bool pred = (double)s > (double)tt / 10.0;   // match numpy float64 promotion
      out[1 + NROW + (tt - 1) * NROW + row] = (pred == pos) ? 1.0f : 0.0f;
    }
  }
  __syncthreads();
  if (t == 0) {
    float bsum = sbce[0] + sbce[1] + sbce[2] + sbce[3]
               + sbce[4] + sbce[5] + sbce[6] + sbce[7];
    atomicAdd(&lossAcc64[(bid & 63) * 16], bsum);   // 64 line-spread slots
  }
}

// ---------------- K4: final loss from 64 spread slots
__global__ void k_loss(const float* __restrict__ lossAcc64, float* __restrict__ out) {
  const int t = threadIdx.x;           // 64 threads
  float v = lossAcc64[t * 16];
  #pragma unroll
  for (int off = 32; off > 0; off >>= 1) v += __shfl_xor(v, off, 64);
  if (t == 0) out[0] = v * (1.0f / NROW);
}

extern "C" void kernel_launch(void* const* d_in, const int* in_sizes, int n_in,
                              void* d_out, int out_size, void* d_ws, size_t ws_size,
                              hipStream_t stream) {
  const float* X     = (const float*)d_in[0];  // cnn_output (256,16,512) == (4096,512)
  const float* W1    = (const float*)d_in[1];  // (1024,256)
  const float* b1    = (const float*)d_in[2];
  const float* gamma = (const float*)d_in[3];
  const float* beta  = (const float*)d_in[4];
  const float* W2    = (const float*)d_in[5];  // (256,1)
  const float* b2    = (const float*)d_in[6];
  float* out = (float*)d_out;

  float* UV        = (float*)d_ws;               // 4096*512
  float* sums8     = UV + (size_t)GM * GN;       // 4096 floats
  float* lossAcc64 = sums8 + 4096;               // 1024 floats (64 slots * 16)
  float* ticket    = lossAcc64 + 1024;           // 1
  float* af        = ticket + 1;                 // 256  (written by k_stats last block)
  float* cf        = af + 256;                   // 256

  hipLaunchKernelGGL(k_gemm,   dim3(512),  dim3(256), 0, stream, X, W1, b1, UV, sums8);
  hipLaunchKernelGGL(k_stats,  dim3(NSTATB), dim3(256), 0, stream, UV, sums8, ticket, gamma, beta, af, cf);
  hipLaunchKernelGGL(k_scores, dim3(7680), dim3(256), 0, stream, UV, af, cf, W2, b2, out, lossAcc64);
  hipLaunchKernelGGL(k_loss,   dim3(1),    dim3(64),  0, stream, lossAcc64, out);
}